// Round 3
// baseline (1165.254 us; speedup 1.0000x reference)
//
#include <hip/hip_runtime.h>
#include <math.h>

#define B_ 32
#define C_ 256
#define H_ 56
#define W_ 56
#define HW_ (H_*W_)        // 3136
#define Q_ (HW_/4)         // 784 float4 positions per (b,c) map
#define R_ 16
#define K_ 7
#define NBLK 1024          // cooperative grid: 4 blocks/CU x 256 CUs

typedef float nat_f4 __attribute__((ext_vector_type(4)));

__device__ __forceinline__ float sigmoidf_(float v) { return 1.0f / (1.0f + __expf(-v)); }

__device__ __forceinline__ void nt_store4(float4 v, float4* p) {
    nat_f4 nv;
    nv.x = v.x; nv.y = v.y; nv.z = v.z; nv.w = v.w;
    __builtin_nontemporal_store(nv, (nat_f4*)p);
}

// Hand-rolled grid barrier: one single-use arrival counter per phase boundary.
// Counters are zeroed by hipMemsetAsync before launch. Only thread 0 of each
// block touches the counter; release via threadfence + ACQ_REL RMW, acquire
// via the RMW release-sequence on the same atomic object.
__device__ __forceinline__ void grid_barrier(unsigned* bar) {
    __syncthreads();
    if (threadIdx.x == 0) {
        __threadfence();   // make this block's prior global writes visible device-wide
        __hip_atomic_fetch_add(bar, 1u, __ATOMIC_ACQ_REL, __HIP_MEMORY_SCOPE_AGENT);
        while (__hip_atomic_load(bar, __ATOMIC_ACQUIRE, __HIP_MEMORY_SCOPE_AGENT) < (unsigned)NBLK) {
            __builtin_amdgcn_s_sleep(1);
        }
        __threadfence();
    }
    __syncthreads();
}

// =====================================================================
// Fused kernel: pool -> mlp(ca) -> spatial pool -> conv(sa) -> finalize,
// with hand-rolled grid barriers between phases.
// 1024 blocks x 256 threads, 4 blocks/CU co-resident (cooperative launch).
// =====================================================================
__global__ void __launch_bounds__(256, 4)
k_cbam_fused(const float* __restrict__ x, const float* __restrict__ w1,
             const float* __restrict__ w2, const float* __restrict__ wsp,
             float* __restrict__ avg, float* __restrict__ mxv, float* __restrict__ ca,
             float* __restrict__ pooled, float* __restrict__ sa, float* __restrict__ out,
             unsigned* __restrict__ bar) {
    const int tid  = threadIdx.x;
    const int lane = tid & 63;
    const int wave = tid >> 6;

    __shared__ float4 ls[256];
    __shared__ float4 lm[256];
    __shared__ float  sA[C_], sM[C_], hh[R_];
    __shared__ float  wconv[2 * K_ * K_];

    // ---------------- Phase 1: per-(b,c) mean + max (wave per map) ----------------
    {
        const int nw = NBLK << 2;                      // 4096 waves in grid
        for (int map = (blockIdx.x << 2) + wave; map < B_ * C_; map += nw) {
            const float4* xp = (const float4*)(x + (size_t)map * HW_);
            float s = 0.0f, m = -INFINITY;
            #pragma unroll
            for (int k = 0; k < 12; ++k) {             // 12*64 = 768 of 784
                float4 v = xp[(k << 6) + lane];
                s += v.x + v.y + v.z + v.w;
                m = fmaxf(m, fmaxf(fmaxf(v.x, v.y), fmaxf(v.z, v.w)));
            }
            if (lane < 16) {                           // tail 768..783
                float4 v = xp[768 + lane];
                s += v.x + v.y + v.z + v.w;
                m = fmaxf(m, fmaxf(fmaxf(v.x, v.y), fmaxf(v.z, v.w)));
            }
            #pragma unroll
            for (int off = 32; off > 0; off >>= 1) {
                s += __shfl_xor(s, off, 64);
                m = fmaxf(m, __shfl_xor(m, off, 64));
            }
            if (lane == 0) {
                avg[map] = s * (1.0f / HW_);
                mxv[map] = m;
            }
        }
    }
    grid_barrier(bar + 0);

    // ---------------- Phase 2: shared MLP -> channel attention (32 blocks) --------
    if (blockIdx.x < B_) {
        const int b = blockIdx.x;
        sA[tid] = avg[b * C_ + tid];
        sM[tid] = mxv[b * C_ + tid];
        __syncthreads();
        if (tid < R_) {
            float ha = 0.0f, hm = 0.0f;
            for (int c = 0; c < C_; ++c) {
                const float wv = w1[tid * C_ + c];
                ha += wv * sA[c];
                hm += wv * sM[c];
            }
            hh[tid] = fmaxf(ha, 0.0f) + fmaxf(hm, 0.0f);
        }
        __syncthreads();
        float acc = 0.0f;
        #pragma unroll
        for (int r = 0; r < R_; ++r) acc += w2[tid * R_ + r] * hh[r];
        ca[b * C_ + tid] = sigmoidf_(acc);
    }
    grid_barrier(bar + 1);

    // ---------------- Phase 3: spatial pooled = {mean_c, max_c} of x*ca -----------
    {
        const int tq = tid & 15;
        const int tc = tid >> 4;
        for (int u = blockIdx.x; u < B_ * 49; u += NBLK) {
            const int b  = u / 49;
            const int q0 = (u - b * 49) << 4;
            const int q  = q0 + tq;
            const float4* xp = (const float4*)(x + (size_t)b * C_ * HW_);
            const float* cab = ca + b * C_;

            float4 s = {0.f, 0.f, 0.f, 0.f};
            float4 m = {-INFINITY, -INFINITY, -INFINITY, -INFINITY};
            #pragma unroll 4
            for (int i = 0; i < 16; ++i) {
                const int c = (tc << 4) + i;
                const float a = cab[c];
                float4 v = xp[(size_t)c * Q_ + q];
                v.x *= a; v.y *= a; v.z *= a; v.w *= a;
                s.x += v.x; s.y += v.y; s.z += v.z; s.w += v.w;
                m.x = fmaxf(m.x, v.x); m.y = fmaxf(m.y, v.y);
                m.z = fmaxf(m.z, v.z); m.w = fmaxf(m.w, v.w);
            }
            ls[tid] = s; lm[tid] = m;
            __syncthreads();
            #pragma unroll
            for (int st = 8; st >= 1; st >>= 1) {
                if (tc < st) {
                    const int o = tid + st * 16;
                    float4 os = ls[o], om = lm[o];
                    s.x += os.x; s.y += os.y; s.z += os.z; s.w += os.w;
                    m.x = fmaxf(m.x, om.x); m.y = fmaxf(m.y, om.y);
                    m.z = fmaxf(m.z, om.z); m.w = fmaxf(m.w, om.w);
                    ls[tid] = s; lm[tid] = m;
                }
                __syncthreads();
            }
            if (tc == 0) {
                const float inv = 1.0f / C_;
                float4 sm4 = {s.x * inv, s.y * inv, s.z * inv, s.w * inv};
                ((float4*)(pooled + (size_t)b * 2 * HW_))[q]       = sm4;
                ((float4*)(pooled + (size_t)b * 2 * HW_ + HW_))[q] = m;
            }
            __syncthreads();
        }
    }
    grid_barrier(bar + 2);

    // ---------------- Phase 4: 7x7 conv + sigmoid -> sa ---------------------------
    {
        if (tid < 2 * K_ * K_) wconv[tid] = wsp[tid];
        __syncthreads();
        const int idx = blockIdx.x * blockDim.x + tid;    // 262144 threads >= 100352
        if (idx < B_ * HW_) {
            const int b  = idx / HW_;
            const int hw = idx % HW_;
            const int h = hw / W_, w = hw % W_;
            const float* pa = pooled + (size_t)b * 2 * HW_;
            const float* pm = pa + HW_;
            float acc = 0.0f;
            #pragma unroll
            for (int ky = 0; ky < K_; ++ky) {
                const int y = h + ky - 3;
                if (y < 0 || y >= H_) continue;
                #pragma unroll
                for (int kx = 0; kx < K_; ++kx) {
                    const int xx = w + kx - 3;
                    if (xx < 0 || xx >= W_) continue;
                    const int o = y * W_ + xx;
                    acc += wconv[ky * K_ + kx] * pa[o] + wconv[K_ * K_ + ky * K_ + kx] * pm[o];
                }
            }
            sa[idx] = sigmoidf_(acc);
        }
    }
    grid_barrier(bar + 3);

    // ---------------- Phase 5: out = x * (1 + ca*sa)  (wave per map) --------------
    {
        const int nw = NBLK << 2;
        for (int map = (blockIdx.x << 2) + wave; map < B_ * C_; map += nw) {
            const int b = map >> 8;                    // C_ == 256
            const float a = ca[map];
            const float4* xp = (const float4*)(x  + (size_t)map * HW_);
            const float4* sp = (const float4*)(sa + (size_t)b * HW_);
            float4* op = (float4*)(out + (size_t)map * HW_);
            #pragma unroll
            for (int k = 0; k < 12; ++k) {
                const int q = (k << 6) + lane;
                float4 v = xp[q], t = sp[q];
                float4 o;
                o.x = v.x * (1.0f + a * t.x);
                o.y = v.y * (1.0f + a * t.y);
                o.z = v.z * (1.0f + a * t.z);
                o.w = v.w * (1.0f + a * t.w);
                nt_store4(o, op + q);
            }
            if (lane < 16) {
                const int q = 768 + lane;
                float4 v = xp[q], t = sp[q];
                float4 o;
                o.x = v.x * (1.0f + a * t.x);
                o.y = v.y * (1.0f + a * t.y);
                o.z = v.z * (1.0f + a * t.z);
                o.w = v.w * (1.0f + a * t.w);
                nt_store4(o, op + q);
            }
        }
    }
}

// =====================================================================
// Fallback path: the proven 5-kernel pipeline (if cooperative launch
// is rejected under graph capture).
// =====================================================================
__global__ void k_pool_bc(const float* __restrict__ x,
                          float* __restrict__ avg, float* __restrict__ mx) {
    const int bc = blockIdx.x;
    const float4* xp = (const float4*)(x + (size_t)bc * HW_);
    float s = 0.0f, m = -INFINITY;
    for (int i = threadIdx.x; i < Q_; i += blockDim.x) {
        float4 v = xp[i];
        s += v.x + v.y + v.z + v.w;
        m = fmaxf(m, fmaxf(fmaxf(v.x, v.y), fmaxf(v.z, v.w)));
    }
    #pragma unroll
    for (int off = 32; off > 0; off >>= 1) {
        s += __shfl_down(s, off, 64);
        m  = fmaxf(m, __shfl_down(m, off, 64));
    }
    __shared__ float ss[4], sm[4];
    const int wave = threadIdx.x >> 6;
    if ((threadIdx.x & 63) == 0) { ss[wave] = s; sm[wave] = m; }
    __syncthreads();
    if (threadIdx.x == 0) {
        float S = ss[0] + ss[1] + ss[2] + ss[3];
        float M = fmaxf(fmaxf(sm[0], sm[1]), fmaxf(sm[2], sm[3]));
        avg[bc] = S * (1.0f / HW_);
        mx[bc]  = M;
    }
}

__global__ void k_mlp_ca(const float* __restrict__ avg, const float* __restrict__ mx,
                         const float* __restrict__ w1, const float* __restrict__ w2,
                         float* __restrict__ ca) {
    const int b = blockIdx.x;
    __shared__ float sa_[C_], sm_[C_], h_[R_];
    const int t = threadIdx.x;
    sa_[t] = avg[b * C_ + t];
    sm_[t] = mx[b * C_ + t];
    __syncthreads();
    if (t < R_) {
        float ha = 0.0f, hm = 0.0f;
        for (int c = 0; c < C_; ++c) {
            const float wv = w1[t * C_ + c];
            ha += wv * sa_[c];
            hm += wv * sm_[c];
        }
        h_[t] = fmaxf(ha, 0.0f) + fmaxf(hm, 0.0f);
    }
    __syncthreads();
    float acc = 0.0f;
    #pragma unroll
    for (int r = 0; r < R_; ++r) acc += w2[t * R_ + r] * h_[r];
    ca[b * C_ + t] = sigmoidf_(acc);
}

__global__ void __launch_bounds__(256)
k_spatial_pool(const float* __restrict__ x, const float* __restrict__ ca,
               float* __restrict__ pooled) {
    const int b  = blockIdx.y;
    const int q0 = blockIdx.x * 16;
    const int t  = threadIdx.x;
    const int tq = t & 15;
    const int tc = t >> 4;
    const int q  = q0 + tq;

    const float4* xp = (const float4*)(x + (size_t)b * C_ * HW_);
    const float* cab = ca + b * C_;

    float4 s = {0.f, 0.f, 0.f, 0.f};
    float4 m = {-INFINITY, -INFINITY, -INFINITY, -INFINITY};
    #pragma unroll 4
    for (int i = 0; i < 16; ++i) {
        const int c = tc * 16 + i;
        const float a = cab[c];
        float4 v = xp[(size_t)c * Q_ + q];
        v.x *= a; v.y *= a; v.z *= a; v.w *= a;
        s.x += v.x; s.y += v.y; s.z += v.z; s.w += v.w;
        m.x = fmaxf(m.x, v.x); m.y = fmaxf(m.y, v.y);
        m.z = fmaxf(m.z, v.z); m.w = fmaxf(m.w, v.w);
    }

    __shared__ float4 ls[256];
    __shared__ float4 lm[256];
    ls[t] = s; lm[t] = m;
    __syncthreads();
    #pragma unroll
    for (int st = 8; st >= 1; st >>= 1) {
        if (tc < st) {
            const int o = t + st * 16;
            float4 os = ls[o], om = lm[o];
            s.x += os.x; s.y += os.y; s.z += os.z; s.w += os.w;
            m.x = fmaxf(m.x, om.x); m.y = fmaxf(m.y, om.y);
            m.z = fmaxf(m.z, om.z); m.w = fmaxf(m.w, om.w);
            ls[t] = s; lm[t] = m;
        }
        __syncthreads();
    }
    if (tc == 0) {
        const float inv = 1.0f / C_;
        float4 sm4 = {s.x * inv, s.y * inv, s.z * inv, s.w * inv};
        ((float4*)(pooled + (size_t)b * 2 * HW_))[q]       = sm4;
        ((float4*)(pooled + (size_t)b * 2 * HW_ + HW_))[q] = m;
    }
}

__global__ void k_conv_sa(const float* __restrict__ pooled, const float* __restrict__ wsp,
                          float* __restrict__ sa) {
    __shared__ float wv[2 * K_ * K_];
    if (threadIdx.x < 2 * K_ * K_) wv[threadIdx.x] = wsp[threadIdx.x];
    __syncthreads();
    const int idx = blockIdx.x * blockDim.x + threadIdx.x;
    if (idx >= B_ * HW_) return;
    const int b = idx / HW_;
    const int hw = idx % HW_;
    const int h = hw / W_, w = hw % W_;
    const float* pa = pooled + (size_t)b * 2 * HW_;
    const float* pm = pa + HW_;
    float acc = 0.0f;
    #pragma unroll
    for (int ky = 0; ky < K_; ++ky) {
        const int y = h + ky - 3;
        if (y < 0 || y >= H_) continue;
        #pragma unroll
        for (int kx = 0; kx < K_; ++kx) {
            const int xx = w + kx - 3;
            if (xx < 0 || xx >= W_) continue;
            const int o = y * W_ + xx;
            acc += wv[ky * K_ + kx] * pa[o] + wv[K_ * K_ + ky * K_ + kx] * pm[o];
        }
    }
    sa[idx] = sigmoidf_(acc);
}

__global__ void k_finalize(const float* __restrict__ x, const float* __restrict__ ca,
                           const float* __restrict__ sa, float* __restrict__ out) {
    const size_t idx = (size_t)blockIdx.x * blockDim.x + threadIdx.x;
    if (idx >= (size_t)B_ * C_ * Q_) return;
    const size_t e = idx * 4;
    const int b  = (int)(e / ((size_t)C_ * HW_));
    const int c  = (int)((e / HW_) % C_);
    const int hw = (int)(e % HW_);
    const float a = ca[b * C_ + c];
    const float4 s4 = *(const float4*)(sa + (size_t)b * HW_ + hw);
    const float4 v  = *(const float4*)(x + e);
    float4 o;
    o.x = v.x * (1.0f + a * s4.x);
    o.y = v.y * (1.0f + a * s4.y);
    o.z = v.z * (1.0f + a * s4.z);
    o.w = v.w * (1.0f + a * s4.w);
    *(float4*)((float*)out + e) = o;
}

extern "C" void kernel_launch(void* const* d_in, const int* in_sizes, int n_in,
                              void* d_out, int out_size, void* d_ws, size_t ws_size,
                              hipStream_t stream) {
    const float* x   = (const float*)d_in[0];
    const float* w1  = (const float*)d_in[1];
    const float* w2  = (const float*)d_in[2];
    const float* wsp = (const float*)d_in[3];
    float* out = (float*)d_out;

    float* ws     = (float*)d_ws;
    float* avg    = ws;                             // B*C
    float* mx     = avg + B_ * C_;                  // B*C
    float* ca     = mx + B_ * C_;                   // B*C
    float* pooled = ca + B_ * C_;                   // B*2*HW
    float* sa     = pooled + (size_t)B_ * 2 * HW_;  // B*HW
    unsigned* bar = (unsigned*)(sa + (size_t)B_ * HW_);  // 4 barrier counters

    // zero the barrier counters (graph-capture-safe async memset on stream)
    hipMemsetAsync((void*)bar, 0, 4 * sizeof(unsigned), stream);

    void* args[] = {(void*)&x, (void*)&w1, (void*)&w2, (void*)&wsp,
                    (void*)&avg, (void*)&mx, (void*)&ca,
                    (void*)&pooled, (void*)&sa, (void*)&out, (void*)&bar};
    hipError_t err = hipLaunchCooperativeKernel((const void*)k_cbam_fused,
                                                dim3(NBLK), dim3(256), args, 0, stream);
    if (err != hipSuccess) {
        // fallback: proven 5-kernel pipeline
        k_pool_bc<<<B_ * C_, 256, 0, stream>>>(x, avg, mx);
        k_mlp_ca<<<B_, C_, 0, stream>>>(avg, mx, w1, w2, ca);
        dim3 g(Q_ / 16, B_);
        k_spatial_pool<<<g, 256, 0, stream>>>(x, ca, pooled);
        const int n = B_ * HW_;
        k_conv_sa<<<(n + 255) / 256, 256, 0, stream>>>(pooled, wsp, sa);
        const size_t nf = (size_t)B_ * C_ * Q_;
        k_finalize<<<(int)((nf + 255) / 256), 256, 0, stream>>>(x, ca, sa, out);
    }
}

// Round 4
// 718.750 us; speedup vs baseline: 1.6212x; 1.6212x over previous
//
#include <hip/hip_runtime.h>
#include <math.h>

#define B_ 32
#define C_ 256
#define H_ 56
#define W_ 56
#define HW_ (H_*W_)        // 3136
#define Q_ (HW_/4)         // 784 float4 positions per (b,c) map
#define R_ 16
#define K_ 7

typedef float nat_f4 __attribute__((ext_vector_type(4)));

__device__ __forceinline__ float sigmoidf_(float v) { return 1.0f / (1.0f + __expf(-v)); }

__device__ __forceinline__ void nt_store4(float4 v, float4* p) {
    nat_f4 nv;
    nv.x = v.x; nv.y = v.y; nv.z = v.z; nv.w = v.w;
    __builtin_nontemporal_store(nv, (nat_f4*)p);
}

// =====================================================================
// K1: per-(b,c) mean+max pooling; the LAST block of each batch b (via a
// non-spinning atomic done-counter) runs the shared MLP -> ca[b,:].
// Grid: 2048 blocks x 256 threads; one wave per map, 4 maps per block,
// 64 blocks per batch. Writers publish avg/mx with agent-scope release
// stores; the last block reads them with agent-scope acquire loads.
// =====================================================================
__global__ void __launch_bounds__(256)
k_pool_mlp(const float* __restrict__ x, const float* __restrict__ w1,
           const float* __restrict__ w2, float* __restrict__ avg,
           float* __restrict__ mxv, float* __restrict__ ca,
           unsigned* __restrict__ done) {
    const int tid  = threadIdx.x;
    const int lane = tid & 63;
    const int wave = tid >> 6;
    const int map  = (blockIdx.x << 2) + wave;     // 0..8191, 4 maps per block
    const int b    = blockIdx.x >> 6;              // 64 blocks per batch

    // ---- pooling: one wave per (b,c) map ----
    {
        const float4* xp = (const float4*)(x + (size_t)map * HW_);
        float s = 0.0f, m = -INFINITY;
        #pragma unroll
        for (int k = 0; k < 12; ++k) {             // 12*64 = 768 of 784
            float4 v = xp[(k << 6) + lane];
            s += v.x + v.y + v.z + v.w;
            m = fmaxf(m, fmaxf(fmaxf(v.x, v.y), fmaxf(v.z, v.w)));
        }
        if (lane < 16) {                           // tail 768..783
            float4 v = xp[768 + lane];
            s += v.x + v.y + v.z + v.w;
            m = fmaxf(m, fmaxf(fmaxf(v.x, v.y), fmaxf(v.z, v.w)));
        }
        #pragma unroll
        for (int off = 32; off > 0; off >>= 1) {
            s += __shfl_xor(s, off, 64);
            m = fmaxf(m, __shfl_xor(m, off, 64));
        }
        if (lane == 0) {
            __hip_atomic_store(&avg[map], s * (1.0f / HW_),
                               __ATOMIC_RELEASE, __HIP_MEMORY_SCOPE_AGENT);
            __hip_atomic_store(&mxv[map], m,
                               __ATOMIC_RELEASE, __HIP_MEMORY_SCOPE_AGENT);
        }
    }

    // ---- last-block-per-b election (single RMW, NO spinning) ----
    __shared__ int isLast;
    __syncthreads();
    if (tid == 0) {
        __threadfence();                            // flush this block's stores agent-wide
        unsigned old = atomicAdd(done + b, 1u);     // device-scope RMW
        isLast = (old == 63u);
    }
    __syncthreads();

    // ---- the last block for b runs the MLP ----
    if (isLast) {
        __shared__ float sA[C_], sM[C_], hh[R_];
        sA[tid] = __hip_atomic_load(&avg[b * C_ + tid],
                                    __ATOMIC_ACQUIRE, __HIP_MEMORY_SCOPE_AGENT);
        sM[tid] = __hip_atomic_load(&mxv[b * C_ + tid],
                                    __ATOMIC_ACQUIRE, __HIP_MEMORY_SCOPE_AGENT);
        __syncthreads();
        if (tid < R_) {
            float ha = 0.0f, hm = 0.0f;
            for (int c = 0; c < C_; ++c) {
                const float wv = w1[tid * C_ + c];
                ha += wv * sA[c];
                hm += wv * sM[c];
            }
            hh[tid] = fmaxf(ha, 0.0f) + fmaxf(hm, 0.0f);
        }
        __syncthreads();
        float acc = 0.0f;
        #pragma unroll
        for (int r = 0; r < R_; ++r) acc += w2[tid * R_ + r] * hh[r];
        ca[b * C_ + tid] = sigmoidf_(acc);
    }
}

// =====================================================================
// K2: spatial pooled = {mean_c, max_c} of x*ca  (proven kernel, unchanged)
// Grid: (49, 32) x 256 threads.
// =====================================================================
__global__ void __launch_bounds__(256)
k_spatial_pool(const float* __restrict__ x, const float* __restrict__ ca,
               float* __restrict__ pooled) {
    const int b  = blockIdx.y;
    const int q0 = blockIdx.x * 16;
    const int t  = threadIdx.x;
    const int tq = t & 15;
    const int tc = t >> 4;
    const int q  = q0 + tq;

    const float4* xp = (const float4*)(x + (size_t)b * C_ * HW_);
    const float* cab = ca + b * C_;

    float4 s = {0.f, 0.f, 0.f, 0.f};
    float4 m = {-INFINITY, -INFINITY, -INFINITY, -INFINITY};
    #pragma unroll 4
    for (int i = 0; i < 16; ++i) {
        const int c = tc * 16 + i;
        const float a = cab[c];
        float4 v = xp[(size_t)c * Q_ + q];
        v.x *= a; v.y *= a; v.z *= a; v.w *= a;
        s.x += v.x; s.y += v.y; s.z += v.z; s.w += v.w;
        m.x = fmaxf(m.x, v.x); m.y = fmaxf(m.y, v.y);
        m.z = fmaxf(m.z, v.z); m.w = fmaxf(m.w, v.w);
    }

    __shared__ float4 ls[256];
    __shared__ float4 lm[256];
    ls[t] = s; lm[t] = m;
    __syncthreads();
    #pragma unroll
    for (int st = 8; st >= 1; st >>= 1) {
        if (tc < st) {
            const int o = t + st * 16;
            float4 os = ls[o], om = lm[o];
            s.x += os.x; s.y += os.y; s.z += os.z; s.w += os.w;
            m.x = fmaxf(m.x, om.x); m.y = fmaxf(m.y, om.y);
            m.z = fmaxf(m.z, om.z); m.w = fmaxf(m.w, om.w);
            ls[t] = s; lm[t] = m;
        }
        __syncthreads();
    }
    if (tc == 0) {
        const float inv = 1.0f / C_;
        float4 sm4 = {s.x * inv, s.y * inv, s.z * inv, s.w * inv};
        ((float4*)(pooled + (size_t)b * 2 * HW_))[q]       = sm4;
        ((float4*)(pooled + (size_t)b * 2 * HW_ + HW_))[q] = m;
    }
}

// =====================================================================
// K3: 7x7 conv + sigmoid -> sa (in LDS) fused with residual finalize.
// Block = (b, 2-row tile): loads pooled halo (8 rows x 62 cols, zero-
// padded) into LDS, computes sa for its 112 positions, then streams all
// 256 channels: coalesced float4 x reads, nontemporal out stores.
// Grid: (28, 32) x 256 threads.
// =====================================================================
__global__ void __launch_bounds__(256)
k_conv_finalize(const float* __restrict__ x, const float* __restrict__ pooled,
                const float* __restrict__ wsp, const float* __restrict__ ca,
                float* __restrict__ out) {
    const int b   = blockIdx.y;
    const int r0  = blockIdx.x * 2;                 // output rows r0, r0+1
    const int tid = threadIdx.x;

    __shared__ float PH[2][8][62];                  // [plane][halo row][padded col]
    __shared__ __align__(16) float ssa[112];        // sa for the 112 tile positions
    __shared__ float sca[C_];
    __shared__ float wc[2 * K_ * K_];

    if (tid < 2 * K_ * K_) wc[tid] = wsp[tid];
    sca[tid] = ca[b * C_ + tid];

    // halo load: 2 planes x 8 rows x 62 cols = 992 entries, zero-padded OOB
    for (int idx = tid; idx < 992; idx += 256) {
        const int plane = idx / 496;
        const int rem   = idx - plane * 496;
        const int lr    = rem / 62;
        const int cpad  = rem - lr * 62;
        const int row   = r0 - 3 + lr;
        const int col   = cpad - 3;
        float v = 0.0f;
        if (row >= 0 && row < H_ && col >= 0 && col < W_)
            v = pooled[((size_t)b * 2 + plane) * HW_ + row * W_ + col];
        PH[plane][lr][cpad] = v;
    }
    __syncthreads();

    // conv 7x7 over the 112 tile positions (zero-padded => no branches)
    if (tid < 112) {
        const int prow = tid / 56;
        const int pcol = tid - prow * 56;
        float acc = 0.0f;
        #pragma unroll
        for (int ky = 0; ky < K_; ++ky) {
            #pragma unroll
            for (int kx = 0; kx < K_; ++kx) {
                acc += wc[ky * K_ + kx]          * PH[0][prow + ky][pcol + kx]
                     + wc[49 + ky * K_ + kx]     * PH[1][prow + ky][pcol + kx];
            }
        }
        ssa[tid] = sigmoidf_(acc);
    }
    __syncthreads();

    // finalize: 8 channels in flight, 28 float4 lanes each (112 floats/ch)
    const int cg   = tid >> 5;                      // 0..7
    const int lane = tid & 31;
    if (lane < 28) {
        const float4* xb = (const float4*)(x + (size_t)b * C_ * HW_);
        float4* ob = (float4*)(out + (size_t)b * C_ * HW_);
        const int base = r0 * 14;                   // float4 offset of row r0
        const float4 s4 = ((const float4*)ssa)[lane];
        #pragma unroll 4
        for (int g = 0; g < 32; ++g) {
            const int c = (g << 3) + cg;
            const float a = sca[c];
            const size_t o = (size_t)c * Q_ + base + lane;
            float4 v = xb[o];
            float4 r;
            r.x = v.x * (1.0f + a * s4.x);
            r.y = v.y * (1.0f + a * s4.y);
            r.z = v.z * (1.0f + a * s4.z);
            r.w = v.w * (1.0f + a * s4.w);
            nt_store4(r, ob + o);
        }
    }
}

extern "C" void kernel_launch(void* const* d_in, const int* in_sizes, int n_in,
                              void* d_out, int out_size, void* d_ws, size_t ws_size,
                              hipStream_t stream) {
    const float* x   = (const float*)d_in[0];
    const float* w1  = (const float*)d_in[1];
    const float* w2  = (const float*)d_in[2];
    const float* wsp = (const float*)d_in[3];
    float* out = (float*)d_out;

    // workspace layout (floats)
    float* ws     = (float*)d_ws;
    float* avg    = ws;                             // B*C
    float* mx     = avg + B_ * C_;                  // B*C
    float* ca     = mx + B_ * C_;                   // B*C
    float* pooled = ca + B_ * C_;                   // B*2*HW
    float* sa_ws  = pooled + (size_t)B_ * 2 * HW_;  // (unused spare, keeps layout)
    unsigned* done = (unsigned*)(sa_ws + (size_t)B_ * HW_);   // B counters

    // zero the per-batch done counters (graph-capture-safe)
    hipMemsetAsync((void*)done, 0, B_ * sizeof(unsigned), stream);

    // K1: pooling + (last block per b) MLP -> ca
    k_pool_mlp<<<(B_ * C_) / 4, 256, 0, stream>>>(x, w1, w2, avg, mx, ca, done);

    // K2: spatial pooling of x*ca
    {
        dim3 g(Q_ / 16, B_);
        k_spatial_pool<<<g, 256, 0, stream>>>(x, ca, pooled);
    }

    // K3: 7x7 conv + sigmoid + residual finalize
    {
        dim3 g(H_ / 2, B_);
        k_conv_finalize<<<g, 256, 0, stream>>>(x, pooled, wsp, ca, out);
    }
}

// Round 5
// 226.641 us; speedup vs baseline: 5.1414x; 3.1713x over previous
//
#include <hip/hip_runtime.h>
#include <math.h>

#define B_ 32
#define C_ 256
#define H_ 56
#define W_ 56
#define HW_ (H_*W_)        // 3136
#define Q_ (HW_/4)         // 784 float4 positions per (b,c) map
#define R_ 16
#define K_ 7

typedef float nat_f4 __attribute__((ext_vector_type(4)));

__device__ __forceinline__ float sigmoidf_(float v) { return 1.0f / (1.0f + __expf(-v)); }

__device__ __forceinline__ void nt_store4(float4 v, float4* p) {
    nat_f4 nv;
    nv.x = v.x; nv.y = v.y; nv.z = v.z; nv.w = v.w;
    __builtin_nontemporal_store(nv, (nat_f4*)p);
}

// =====================================================================
// K1: per-(b,c) mean+max pooling. One wave per map, 4 maps per block.
// PLAIN stores only — no atomics, no fences (kernel boundary orders).
// Grid: 2048 blocks x 256 threads.
// =====================================================================
__global__ void __launch_bounds__(256)
k_pool(const float* __restrict__ x, float* __restrict__ avg,
       float* __restrict__ mxv) {
    const int tid  = threadIdx.x;
    const int lane = tid & 63;
    const int wave = tid >> 6;
    const int map  = (blockIdx.x << 2) + wave;     // 0..8191

    const float4* xp = (const float4*)(x + (size_t)map * HW_);
    float s = 0.0f, m = -INFINITY;
    #pragma unroll
    for (int k = 0; k < 12; ++k) {                 // 12*64 = 768 of 784
        float4 v = xp[(k << 6) + lane];
        s += v.x + v.y + v.z + v.w;
        m = fmaxf(m, fmaxf(fmaxf(v.x, v.y), fmaxf(v.z, v.w)));
    }
    if (lane < 16) {                               // tail 768..783
        float4 v = xp[768 + lane];
        s += v.x + v.y + v.z + v.w;
        m = fmaxf(m, fmaxf(fmaxf(v.x, v.y), fmaxf(v.z, v.w)));
    }
    #pragma unroll
    for (int off = 32; off > 0; off >>= 1) {
        s += __shfl_xor(s, off, 64);
        m = fmaxf(m, __shfl_xor(m, off, 64));
    }
    if (lane == 0) {
        avg[map] = s * (1.0f / HW_);
        mxv[map] = m;
    }
}

// =====================================================================
// K2: shared MLP -> channel attention. Grid: 32 blocks x 256 threads.
// =====================================================================
__global__ void __launch_bounds__(256)
k_mlp_ca(const float* __restrict__ avg, const float* __restrict__ mx,
         const float* __restrict__ w1, const float* __restrict__ w2,
         float* __restrict__ ca) {
    const int b = blockIdx.x;
    __shared__ float sa_[C_], sm_[C_], h_[R_];
    const int t = threadIdx.x;
    sa_[t] = avg[b * C_ + t];
    sm_[t] = mx[b * C_ + t];
    __syncthreads();
    if (t < R_) {
        float ha = 0.0f, hm = 0.0f;
        for (int c = 0; c < C_; ++c) {
            const float wv = w1[t * C_ + c];
            ha += wv * sa_[c];
            hm += wv * sm_[c];
        }
        h_[t] = fmaxf(ha, 0.0f) + fmaxf(hm, 0.0f);
    }
    __syncthreads();
    float acc = 0.0f;
    #pragma unroll
    for (int r = 0; r < R_; ++r) acc += w2[t * R_ + r] * h_[r];
    ca[b * C_ + t] = sigmoidf_(acc);
}

// =====================================================================
// K3: spatial pooled = {mean_c, max_c} of x*ca.
// Wave = 64 consecutive float4 q-positions; each wave accumulates its
// own 64-channel slice fully in registers (coalesced 1KB/wave/channel),
// then a single 4-way LDS reduce across waves. 2 barriers total.
// Grid: (ceil(Q_/64)=13, 32) x 256 threads.
// =====================================================================
__global__ void __launch_bounds__(256)
k_spatial_pool(const float* __restrict__ x, const float* __restrict__ ca,
               float* __restrict__ pooled) {
    const int b    = blockIdx.y;
    const int tid  = threadIdx.x;
    const int lane = tid & 63;
    const int w    = tid >> 6;                      // wave -> channel slice
    const int q    = blockIdx.x * 64 + lane;        // float4 index
    const bool valid = (q < Q_);

    const float4* xb = (const float4*)(x + (size_t)b * C_ * HW_);
    const float* cab = ca + b * C_;

    float4 s = {0.f, 0.f, 0.f, 0.f};
    float4 m = {-INFINITY, -INFINITY, -INFINITY, -INFINITY};
    if (valid) {
        #pragma unroll 8
        for (int i = 0; i < 64; ++i) {
            const int c = (w << 6) + i;
            const float a = cab[c];
            float4 v = xb[(size_t)c * Q_ + q];
            v.x *= a; v.y *= a; v.z *= a; v.w *= a;
            s.x += v.x; s.y += v.y; s.z += v.z; s.w += v.w;
            m.x = fmaxf(m.x, v.x); m.y = fmaxf(m.y, v.y);
            m.z = fmaxf(m.z, v.z); m.w = fmaxf(m.w, v.w);
        }
    }

    __shared__ float4 ps[4][64];
    __shared__ float4 pm[4][64];
    ps[w][lane] = s; pm[w][lane] = m;
    __syncthreads();
    if (w == 0 && valid) {
        #pragma unroll
        for (int k = 1; k < 4; ++k) {
            float4 os = ps[k][lane], om = pm[k][lane];
            s.x += os.x; s.y += os.y; s.z += os.z; s.w += os.w;
            m.x = fmaxf(m.x, om.x); m.y = fmaxf(m.y, om.y);
            m.z = fmaxf(m.z, om.z); m.w = fmaxf(m.w, om.w);
        }
        const float inv = 1.0f / C_;
        float4 sm4 = {s.x * inv, s.y * inv, s.z * inv, s.w * inv};
        ((float4*)(pooled + (size_t)b * 2 * HW_))[q]       = sm4;
        ((float4*)(pooled + (size_t)b * 2 * HW_ + HW_))[q] = m;
    }
}

// =====================================================================
// K4: 7x7 conv + sigmoid -> sa (in LDS) fused with residual finalize.
// Block = (b, 2-row tile): pooled halo (8x62, zero-padded) in LDS,
// conv for 112 positions, then stream all 256 channels.
// Grid: (28, 32) x 256 threads.  (proven in round 4)
// =====================================================================
__global__ void __launch_bounds__(256)
k_conv_finalize(const float* __restrict__ x, const float* __restrict__ pooled,
                const float* __restrict__ wsp, const float* __restrict__ ca,
                float* __restrict__ out) {
    const int b   = blockIdx.y;
    const int r0  = blockIdx.x * 2;                 // output rows r0, r0+1
    const int tid = threadIdx.x;

    __shared__ float PH[2][8][62];                  // [plane][halo row][padded col]
    __shared__ __align__(16) float ssa[112];        // sa for the 112 tile positions
    __shared__ float sca[C_];
    __shared__ float wc[2 * K_ * K_];

    if (tid < 2 * K_ * K_) wc[tid] = wsp[tid];
    sca[tid] = ca[b * C_ + tid];

    // halo load: 2 planes x 8 rows x 62 cols = 992 entries, zero-padded OOB
    for (int idx = tid; idx < 992; idx += 256) {
        const int plane = idx / 496;
        const int rem   = idx - plane * 496;
        const int lr    = rem / 62;
        const int cpad  = rem - lr * 62;
        const int row   = r0 - 3 + lr;
        const int col   = cpad - 3;
        float v = 0.0f;
        if (row >= 0 && row < H_ && col >= 0 && col < W_)
            v = pooled[((size_t)b * 2 + plane) * HW_ + row * W_ + col];
        PH[plane][lr][cpad] = v;
    }
    __syncthreads();

    // conv 7x7 over the 112 tile positions (zero-padded => no branches)
    if (tid < 112) {
        const int prow = tid / 56;
        const int pcol = tid - prow * 56;
        float acc = 0.0f;
        #pragma unroll
        for (int ky = 0; ky < K_; ++ky) {
            #pragma unroll
            for (int kx = 0; kx < K_; ++kx) {
                acc += wc[ky * K_ + kx]          * PH[0][prow + ky][pcol + kx]
                     + wc[49 + ky * K_ + kx]     * PH[1][prow + ky][pcol + kx];
            }
        }
        ssa[tid] = sigmoidf_(acc);
    }
    __syncthreads();

    // finalize: 8 channels in flight, 28 float4 lanes each (112 floats/ch)
    const int cg   = tid >> 5;                      // 0..7
    const int lane = tid & 31;
    if (lane < 28) {
        const float4* xb = (const float4*)(x + (size_t)b * C_ * HW_);
        float4* ob = (float4*)(out + (size_t)b * C_ * HW_);
        const int base = r0 * 14;                   // float4 offset of row r0
        const float4 s4 = ((const float4*)ssa)[lane];
        #pragma unroll 4
        for (int g = 0; g < 32; ++g) {
            const int c = (g << 3) + cg;
            const float a = sca[c];
            const size_t o = (size_t)c * Q_ + base + lane;
            float4 v = xb[o];
            float4 r;
            r.x = v.x * (1.0f + a * s4.x);
            r.y = v.y * (1.0f + a * s4.y);
            r.z = v.z * (1.0f + a * s4.z);
            r.w = v.w * (1.0f + a * s4.w);
            nt_store4(r, ob + o);
        }
    }
}

extern "C" void kernel_launch(void* const* d_in, const int* in_sizes, int n_in,
                              void* d_out, int out_size, void* d_ws, size_t ws_size,
                              hipStream_t stream) {
    const float* x   = (const float*)d_in[0];
    const float* w1  = (const float*)d_in[1];
    const float* w2  = (const float*)d_in[2];
    const float* wsp = (const float*)d_in[3];
    float* out = (float*)d_out;

    // workspace layout (floats)
    float* ws     = (float*)d_ws;
    float* avg    = ws;                             // B*C
    float* mx     = avg + B_ * C_;                  // B*C
    float* ca     = mx + B_ * C_;                   // B*C
    float* pooled = ca + B_ * C_;                   // B*2*HW

    // K1: channel-wise pooling (plain stores; boundary orders)
    k_pool<<<(B_ * C_) / 4, 256, 0, stream>>>(x, avg, mx);

    // K2: MLP -> channel attention
    k_mlp_ca<<<B_, 256, 0, stream>>>(avg, mx, w1, w2, ca);

    // K3: spatial pooling of x*ca
    {
        dim3 g((Q_ + 63) / 64, B_);
        k_spatial_pool<<<g, 256, 0, stream>>>(x, ca, pooled);
    }

    // K4: 7x7 conv + sigmoid + residual finalize
    {
        dim3 g(H_ / 2, B_);
        k_conv_finalize<<<g, 256, 0, stream>>>(x, pooled, wsp, ca, out);
    }
}

// Round 6
// 224.749 us; speedup vs baseline: 5.1847x; 1.0084x over previous
//
#include <hip/hip_runtime.h>
#include <math.h>

#define B_ 32
#define C_ 256
#define H_ 56
#define W_ 56
#define HW_ (H_*W_)        // 3136
#define Q_ (HW_/4)         // 784 float4 positions per (b,c) map
#define R_ 16
#define K_ 7

typedef float nat_f4 __attribute__((ext_vector_type(4)));

__device__ __forceinline__ float sigmoidf_(float v) { return 1.0f / (1.0f + __expf(-v)); }

__device__ __forceinline__ void nt_store4(float4 v, float4* p) {
    nat_f4 nv;
    nv.x = v.x; nv.y = v.y; nv.z = v.z; nv.w = v.w;
    __builtin_nontemporal_store(nv, (nat_f4*)p);
}

// ---------------------------------------------------------------------
// Block-parallel shared-MLP channel attention, recomputed per block.
// All 256 threads participate. Cost ~100 cycles; w1/w2 are L2-hot.
// h[r] = relu(sum_c w1[r,c]*avg[c]) + relu(sum_c w1[r,c]*max[c])
// ca[c] = sigmoid(sum_r w2[c,r]*h[r])
// ---------------------------------------------------------------------
__device__ __forceinline__ void mlp_ca_block(int b,
        const float* __restrict__ avg, const float* __restrict__ mxv,
        const float* __restrict__ w1, const float* __restrict__ w2,
        float* sA, float* sM, float* hh, float* sca) {
    const int t = threadIdx.x;
    sA[t] = avg[b * C_ + t];
    sM[t] = mxv[b * C_ + t];
    __syncthreads();
    const int r = t >> 4, seg = t & 15;             // 16 threads per hidden unit
    float pa = 0.f, pm = 0.f;
    #pragma unroll
    for (int i = 0; i < 16; ++i) {
        const float wv = w1[r * C_ + seg * 16 + i];
        pa += wv * sA[seg * 16 + i];
        pm += wv * sM[seg * 16 + i];
    }
    #pragma unroll
    for (int off = 8; off >= 1; off >>= 1) {        // reduce across the 16-lane group
        pa += __shfl_xor(pa, off, 64);
        pm += __shfl_xor(pm, off, 64);
    }
    if (seg == 0) hh[r] = fmaxf(pa, 0.f) + fmaxf(pm, 0.f);
    __syncthreads();
    float acc = 0.f;
    #pragma unroll
    for (int rr = 0; rr < R_; ++rr) acc += w2[t * R_ + rr] * hh[rr];
    sca[t] = sigmoidf_(acc);
    __syncthreads();
}

// =====================================================================
// K1: per-(b,c) mean+max pooling. One wave per map, 4 maps per block.
// Plain stores; kernel boundary provides ordering/coherence.
// Grid: 2048 blocks x 256 threads.
// =====================================================================
__global__ void __launch_bounds__(256)
k_pool(const float* __restrict__ x, float* __restrict__ avg,
       float* __restrict__ mxv) {
    const int tid  = threadIdx.x;
    const int lane = tid & 63;
    const int wave = tid >> 6;
    const int map  = (blockIdx.x << 2) + wave;     // 0..8191

    const float4* xp = (const float4*)(x + (size_t)map * HW_);
    float s = 0.0f, m = -INFINITY;
    #pragma unroll
    for (int k = 0; k < 12; ++k) {                 // 12*64 = 768 of 784
        float4 v = xp[(k << 6) + lane];
        s += v.x + v.y + v.z + v.w;
        m = fmaxf(m, fmaxf(fmaxf(v.x, v.y), fmaxf(v.z, v.w)));
    }
    if (lane < 16) {                               // tail 768..783
        float4 v = xp[768 + lane];
        s += v.x + v.y + v.z + v.w;
        m = fmaxf(m, fmaxf(fmaxf(v.x, v.y), fmaxf(v.z, v.w)));
    }
    #pragma unroll
    for (int off = 32; off > 0; off >>= 1) {
        s += __shfl_xor(s, off, 64);
        m = fmaxf(m, __shfl_xor(m, off, 64));
    }
    if (lane == 0) {
        avg[map] = s * (1.0f / HW_);
        mxv[map] = m;
    }
}

// =====================================================================
// K2: spatial pooled = {mean_c, max_c} of x*ca, with MLP fused in.
// Grid: (49, 32) x 256 threads (1568 blocks -> good CU balance).
// =====================================================================
__global__ void __launch_bounds__(256)
k_spatial_pool(const float* __restrict__ x, const float* __restrict__ avg,
               const float* __restrict__ mxv, const float* __restrict__ w1,
               const float* __restrict__ w2, float* __restrict__ pooled) {
    const int b  = blockIdx.y;
    const int q0 = blockIdx.x * 16;
    const int t  = threadIdx.x;
    const int tq = t & 15;
    const int tc = t >> 4;
    const int q  = q0 + tq;

    __shared__ float sA[C_], sM[C_], sca[C_], hh[R_];
    mlp_ca_block(b, avg, mxv, w1, w2, sA, sM, hh, sca);

    const float4* xp = (const float4*)(x + (size_t)b * C_ * HW_);

    float4 s = {0.f, 0.f, 0.f, 0.f};
    float4 m = {-INFINITY, -INFINITY, -INFINITY, -INFINITY};
    #pragma unroll 4
    for (int i = 0; i < 16; ++i) {
        const int c = tc * 16 + i;
        const float a = sca[c];
        float4 v = xp[(size_t)c * Q_ + q];
        v.x *= a; v.y *= a; v.z *= a; v.w *= a;
        s.x += v.x; s.y += v.y; s.z += v.z; s.w += v.w;
        m.x = fmaxf(m.x, v.x); m.y = fmaxf(m.y, v.y);
        m.z = fmaxf(m.z, v.z); m.w = fmaxf(m.w, v.w);
    }

    __shared__ float4 ls[256];
    __shared__ float4 lm[256];
    ls[t] = s; lm[t] = m;
    __syncthreads();
    #pragma unroll
    for (int st = 8; st >= 1; st >>= 1) {
        if (tc < st) {
            const int o = t + st * 16;
            float4 os = ls[o], om = lm[o];
            s.x += os.x; s.y += os.y; s.z += os.z; s.w += os.w;
            m.x = fmaxf(m.x, om.x); m.y = fmaxf(m.y, om.y);
            m.z = fmaxf(m.z, om.z); m.w = fmaxf(m.w, om.w);
            ls[t] = s; lm[t] = m;
        }
        __syncthreads();
    }
    if (tc == 0) {
        const float inv = 1.0f / C_;
        float4 sm4 = {s.x * inv, s.y * inv, s.z * inv, s.w * inv};
        ((float4*)(pooled + (size_t)b * 2 * HW_))[q]       = sm4;
        ((float4*)(pooled + (size_t)b * 2 * HW_ + HW_))[q] = m;
    }
}

// =====================================================================
// K3: 7x7 conv + sigmoid -> sa (in LDS) fused with residual finalize,
// with MLP fused in (recompute ca from avg/mx; no ca round-trip).
// Block = (b, 2-row tile). Grid: (28, 32) x 256 threads.
// =====================================================================
__global__ void __launch_bounds__(256)
k_conv_finalize(const float* __restrict__ x, const float* __restrict__ pooled,
                const float* __restrict__ wsp, const float* __restrict__ avg,
                const float* __restrict__ mxv, const float* __restrict__ w1,
                const float* __restrict__ w2, float* __restrict__ out) {
    const int b   = blockIdx.y;
    const int r0  = blockIdx.x * 2;                 // output rows r0, r0+1
    const int tid = threadIdx.x;

    __shared__ float PH[2][8][62];                  // [plane][halo row][padded col]
    __shared__ __align__(16) float ssa[112];        // sa for the 112 tile positions
    __shared__ float sA[C_], sM[C_], sca[C_], hh[R_];
    __shared__ float wc[2 * K_ * K_];

    if (tid < 2 * K_ * K_) wc[tid] = wsp[tid];
    mlp_ca_block(b, avg, mxv, w1, w2, sA, sM, hh, sca);

    // halo load: 2 planes x 8 rows x 62 cols = 992 entries, zero-padded OOB
    for (int idx = tid; idx < 992; idx += 256) {
        const int plane = idx / 496;
        const int rem   = idx - plane * 496;
        const int lr    = rem / 62;
        const int cpad  = rem - lr * 62;
        const int row   = r0 - 3 + lr;
        const int col   = cpad - 3;
        float v = 0.0f;
        if (row >= 0 && row < H_ && col >= 0 && col < W_)
            v = pooled[((size_t)b * 2 + plane) * HW_ + row * W_ + col];
        PH[plane][lr][cpad] = v;
    }
    __syncthreads();

    // conv 7x7 over the 112 tile positions (zero-padded => no branches)
    if (tid < 112) {
        const int prow = tid / 56;
        const int pcol = tid - prow * 56;
        float acc = 0.0f;
        #pragma unroll
        for (int ky = 0; ky < K_; ++ky) {
            #pragma unroll
            for (int kx = 0; kx < K_; ++kx) {
                acc += wc[ky * K_ + kx]          * PH[0][prow + ky][pcol + kx]
                     + wc[49 + ky * K_ + kx]     * PH[1][prow + ky][pcol + kx];
            }
        }
        ssa[tid] = sigmoidf_(acc);
    }
    __syncthreads();

    // finalize: 8 channels in flight, 28 float4 lanes each (112 floats/ch)
    const int cg   = tid >> 5;                      // 0..7
    const int lane = tid & 31;
    if (lane < 28) {
        const float4* xb = (const float4*)(x + (size_t)b * C_ * HW_);
        float4* ob = (float4*)(out + (size_t)b * C_ * HW_);
        const int base = r0 * 14;                   // float4 offset of row r0
        const float4 s4 = ((const float4*)ssa)[lane];
        #pragma unroll 4
        for (int g = 0; g < 32; ++g) {
            const int c = (g << 3) + cg;
            const float a = sca[c];
            const size_t o = (size_t)c * Q_ + base + lane;
            float4 v = xb[o];
            float4 r;
            r.x = v.x * (1.0f + a * s4.x);
            r.y = v.y * (1.0f + a * s4.y);
            r.z = v.z * (1.0f + a * s4.z);
            r.w = v.w * (1.0f + a * s4.w);
            nt_store4(r, ob + o);
        }
    }
}

extern "C" void kernel_launch(void* const* d_in, const int* in_sizes, int n_in,
                              void* d_out, int out_size, void* d_ws, size_t ws_size,
                              hipStream_t stream) {
    const float* x   = (const float*)d_in[0];
    const float* w1  = (const float*)d_in[1];
    const float* w2  = (const float*)d_in[2];
    const float* wsp = (const float*)d_in[3];
    float* out = (float*)d_out;

    // workspace layout (floats)
    float* ws     = (float*)d_ws;
    float* avg    = ws;                             // B*C
    float* mx     = avg + B_ * C_;                  // B*C
    float* pooled = mx + B_ * C_;                   // B*2*HW

    // K1: channel-wise pooling
    k_pool<<<(B_ * C_) / 4, 256, 0, stream>>>(x, avg, mx);

    // K2: spatial pooling of x*ca (MLP fused per block)
    {
        dim3 g(Q_ / 16, B_);
        k_spatial_pool<<<g, 256, 0, stream>>>(x, avg, mx, w1, w2, pooled);
    }

    // K3: 7x7 conv + sigmoid + residual finalize (MLP fused per block)
    {
        dim3 g(H_ / 2, B_);
        k_conv_finalize<<<g, 256, 0, stream>>>(x, pooled, wsp, avg, mx, w1, w2, out);
    }
}